// Round 3
// baseline (272.055 us; speedup 1.0000x reference)
//
#include <hip/hip_runtime.h>
#include <hip/hip_fp16.h>

#define D 128
#define EPS 1e-5f
#define CB 128         // count blocks fused ahead of GEMM1

typedef unsigned int u32;
typedef unsigned short u16;
typedef unsigned char u8;
typedef __attribute__((ext_vector_type(8))) _Float16 half8;  // mfma A/B frag
typedef __attribute__((ext_vector_type(4))) float f32x4;
typedef __attribute__((ext_vector_type(2))) float f32x2;

__device__ inline u16 f2h(float x) {
  _Float16 t = (_Float16)x;
  return __builtin_bit_cast(u16, t);
}
__device__ inline u8 f2fp8(float x) {
  return (u8)(__builtin_amdgcn_cvt_pk_fp8_f32(x, x, 0, false) & 0xff);
}

// ---------------------------------------------------------------------------
// P0: convert W1,W2 fp32[k][c] -> fp16 Wt[c][k]  ||  zero deg[N].
__global__ __launch_bounds__(256) void k_prep(const float* __restrict__ W1,
                                              const float* __restrict__ W2,
                                              u16* __restrict__ Wt1,
                                              u16* __restrict__ Wt2,
                                              int* __restrict__ deg, int N) {
  if (blockIdx.x < 128) {
    int i = blockIdx.x * 256 + threadIdx.x;
    const float* W = (i < D * D) ? W1 : W2;
    u16* Wt = (i < D * D) ? Wt1 : Wt2;
    int ii = i & (D * D - 1);
    int k = ii >> 7, c = ii & 127;
    Wt[c * D + k] = f2h(W[ii]);
  } else {
    int i = (blockIdx.x - 128) * 256 + threadIdx.x;
    if (i < N) deg[i] = 0;
  }
}

// ---------------------------------------------------------------------------
// LDS-free MFMA GEMM body; OUTPUT IS FP8 (e4m3). A-frag from global
// (contiguous 16B in k); B from Wt[c][k] (L2-hot); D: col=ct*16+m, row=q*4+reg.
template <bool F32IN>
__device__ __forceinline__ void gemm_body(const void* __restrict__ in_,
                                          const u16* __restrict__ Wt,
                                          u8* __restrict__ out, int nrows,
                                          int blk) {
  const int tid = threadIdx.x;
  const int lane = tid & 63, wv = tid >> 6;
  const int m = lane & 15, q = lane >> 4;
  const int r0 = blk * 64 + wv * 16;
  const int rowa = min(r0 + m, nrows - 1);

  f32x4 acc[8];
#pragma unroll
  for (int ct = 0; ct < 8; ct++) acc[ct] = (f32x4)(0.0f);

#pragma unroll
  for (int kk = 0; kk < 4; kk++) {
    const int kbase = kk * 32 + q * 8;
    half8 a;
    if (F32IN) {
      const float* in = (const float*)in_;
      float4 v0 = *(const float4*)(in + (size_t)rowa * D + kbase);
      float4 v1 = *(const float4*)(in + (size_t)rowa * D + kbase + 4);
      a[0] = (_Float16)v0.x; a[1] = (_Float16)v0.y;
      a[2] = (_Float16)v0.z; a[3] = (_Float16)v0.w;
      a[4] = (_Float16)v1.x; a[5] = (_Float16)v1.y;
      a[6] = (_Float16)v1.z; a[7] = (_Float16)v1.w;
    } else {
      const u16* in = (const u16*)in_;
      a = *(const half8*)(in + (size_t)rowa * D + kbase);
    }
#pragma unroll
    for (int ct = 0; ct < 8; ct++) {
      half8 b = *(const half8*)(Wt + (ct * 16 + m) * D + kbase);
      acc[ct] = __builtin_amdgcn_mfma_f32_16x16x32_f16(a, b, acc[ct], 0, 0, 0);
    }
  }

#pragma unroll
  for (int ct = 0; ct < 8; ct++) {
#pragma unroll
    for (int rg = 0; rg < 4; rg++) {
      int rr = r0 + q * 4 + rg;
      if (rr < nrows) out[(size_t)rr * D + ct * 16 + m] = f2fp8(acc[ct][rg]);
    }
  }
}

// ph1: deg count via global atomics (blocks [0,CB)) || GEMM1.
__global__ __launch_bounds__(256) void k_count_gemm1(
    const int* __restrict__ dst, int* __restrict__ deg, int E, int EPB,
    const float* __restrict__ x, const u16* __restrict__ Wt1,
    u8* __restrict__ A, int nrows) {
  if (blockIdx.x < (u32)CB) {
    const int k = blockIdx.x, tid = threadIdx.x;
    const int e0 = k * EPB, e1 = min(E, e0 + EPB);
    for (int base = e0 + tid; base < e1; base += 1024) {
      int dd[4];
#pragma unroll
      for (int i = 0; i < 4; i++) {
        int e = base + i * 256;
        dd[i] = (e < e1) ? dst[e] : -1;
      }
#pragma unroll
      for (int i = 0; i < 4; i++)
        if (dd[i] >= 0) atomicAdd(&deg[dd[i]], 1);
    }
  } else {
    gemm_body<true>(x, Wt1, A, nrows, blockIdx.x - CB);
  }
}

// ph2: single-block exclusive scan of deg[N] -> meta/dinv/cursor.
__global__ __launch_bounds__(1024) void k_scan(const int* __restrict__ deg,
                                               int4* __restrict__ meta,
                                               float* __restrict__ dinv,
                                               int* __restrict__ cursor,
                                               int N) {
  __shared__ int wt[16];
  const int tid = threadIdx.x;
  const int lane = tid & 63, wid = tid >> 6;
  const int chunks = (N + 1023) >> 10;
  int running = 0;
  int i = tid;
  int v = (i < N) ? deg[i] : 0;
  for (int c = 0; c < chunks; c++) {
    int inext = i + 1024;
    int vnext = (c + 1 < chunks && inext < N) ? deg[inext] : 0;
    int incl = v;
#pragma unroll
    for (int o = 1; o < 64; o <<= 1) {
      int t = __shfl_up(incl, o, 64);
      if (lane >= o) incl += t;
    }
    if (lane == 63) wt[wid] = incl;
    __syncthreads();
    int woff = 0, total = 0;
#pragma unroll
    for (int j = 0; j < 16; j++) {
      int t = wt[j];
      if (j < wid) woff += t;
      total += t;
    }
    int excl = running + woff + incl - v;
    if (i < N) {
      float dv = rsqrtf((float)v + 1.0f);
      meta[i] = make_int4(excl, v, __builtin_bit_cast(int, dv), 0);
      dinv[i] = dv;
      cursor[i] = excl;
    }
    running += total;
    __syncthreads();
    i = inext;
    v = vnext;
  }
}

// ph3: direct scatter: csr[atomicInc(cursor[dst])] = src | fp16(w)<<16.
// Weight computed inline (dinv L2-hot). Entry order within a node is
// arrival-order (non-deterministic) -> only reorders fp32 accumulation.
__global__ __launch_bounds__(256) void k_scatter2(
    const int* __restrict__ src, const int* __restrict__ dst,
    const float* __restrict__ dinv, int* __restrict__ cursor,
    u32* __restrict__ csr, int E) {
  const int stride = gridDim.x * 256;
  int gid = blockIdx.x * 256 + threadIdx.x;
  for (int base = gid; base < E; base += stride * 4) {
    int ss[4], dd[4];
#pragma unroll
    for (int i = 0; i < 4; i++) {
      int e = base + i * stride;
      ss[i] = (e < E) ? src[e] : 0;
      dd[i] = (e < E) ? dst[e] : -1;
    }
    float ws[4], wd[4];
#pragma unroll
    for (int i = 0; i < 4; i++) {
      ws[i] = (dd[i] >= 0) ? dinv[ss[i]] : 0.0f;
      wd[i] = (dd[i] >= 0) ? dinv[dd[i]] : 0.0f;
    }
#pragma unroll
    for (int i = 0; i < 4; i++) {
      if (dd[i] >= 0) {
        int p = atomicAdd(&cursor[dd[i]], 1);
        csr[p] = (u32)ss[i] | ((u32)f2h(ws[i] * wd[i]) << 16);
      }
    }
  }
}

// ---------------------------------------------------------------------------
// Gather+LN core — FP8 h rows (128 B), fp32 accumulation.
// Row owned by 16 lanes, uint2 (8 fp8) per lane.
// csr entries fetched as UNIFORM per-group vector loads (HW broadcast) —
// affine addresses, no ds_bpermute in the chase chain. 8 row loads issued
// back-to-back per window.
#define ACC_EDGE(vv, ee)                                                     \
  {                                                                          \
    float ww = (float)__builtin_bit_cast(_Float16, (u16)((ee) >> 16));       \
    f32x2 p_;                                                                \
    p_ = __builtin_amdgcn_cvt_pk_f32_fp8(vv.x, false);                       \
    acc[0] = fmaf(p_[0], ww, acc[0]); acc[1] = fmaf(p_[1], ww, acc[1]);      \
    p_ = __builtin_amdgcn_cvt_pk_f32_fp8(vv.x, true);                        \
    acc[2] = fmaf(p_[0], ww, acc[2]); acc[3] = fmaf(p_[1], ww, acc[3]);      \
    p_ = __builtin_amdgcn_cvt_pk_f32_fp8(vv.y, false);                       \
    acc[4] = fmaf(p_[0], ww, acc[4]); acc[5] = fmaf(p_[1], ww, acc[5]);      \
    p_ = __builtin_amdgcn_cvt_pk_f32_fp8(vv.y, true);                        \
    acc[6] = fmaf(p_[0], ww, acc[6]); acc[7] = fmaf(p_[1], ww, acc[7]);      \
  }

__device__ __forceinline__ void gather_ln_core(
    const uint2* __restrict__ hb, const int4* __restrict__ meta,
    const u32* __restrict__ csr, const float* __restrict__ b,
    const float* __restrict__ g, const float* __restrict__ bln,
    int row, int n, int sl, float out[8]) {
  const bool valid = row < n;
  const int rc = valid ? row : 0;
  int4 mt = meta[rc];
  int beg = mt.x;
  int cnt = valid ? mt.y : 0;
  float dv = __builtin_bit_cast(float, mt.z);
  float sn = dv * dv;

  float acc[8];
  {
    uint2 su = hb[(size_t)rc * 16 + sl];
    f32x2 p0 = __builtin_amdgcn_cvt_pk_f32_fp8(su.x, false);
    f32x2 p1 = __builtin_amdgcn_cvt_pk_f32_fp8(su.x, true);
    f32x2 p2 = __builtin_amdgcn_cvt_pk_f32_fp8(su.y, false);
    f32x2 p3 = __builtin_amdgcn_cvt_pk_f32_fp8(su.y, true);
    acc[0] = p0[0] * sn; acc[1] = p0[1] * sn;
    acc[2] = p1[0] * sn; acc[3] = p1[1] * sn;
    acc[4] = p2[0] * sn; acc[5] = p2[1] * sn;
    acc[6] = p3[0] * sn; acc[7] = p3[1] * sn;
  }

  int cm = max(cnt, __shfl_xor(cnt, 16, 64));
  cm = max(cm, __shfl_xor(cm, 32, 64));

  for (int j0 = 0; j0 < cm; j0 += 8) {
    u32 e[8];
#pragma unroll
    for (int jj = 0; jj < 8; jj++) {
      int j = j0 + jj;
      e[jj] = (j < cnt) ? csr[beg + j] : 0u;   // uniform per 16-lane group
    }
    uint2 v[8];
#pragma unroll
    for (int jj = 0; jj < 8; jj++)
      v[jj] = hb[(size_t)(e[jj] & 0xffffu) * 16 + sl];
#pragma unroll
    for (int jj = 0; jj < 8; jj++) ACC_EDGE(v[jj], e[jj]);
  }

  // ---- LayerNorm over 128 cols, 8 per lane across 16 lanes ----
  int d0 = sl * 8;
  float4 bb0 = *(const float4*)(b + d0);
  float4 bb1 = *(const float4*)(b + d0 + 4);
  float a0 = acc[0] + bb0.x, a1 = acc[1] + bb0.y;
  float a2 = acc[2] + bb0.z, a3 = acc[3] + bb0.w;
  float a4 = acc[4] + bb1.x, a5 = acc[5] + bb1.y;
  float a6 = acc[6] + bb1.z, a7 = acc[7] + bb1.w;

  float sum = ((a0 + a1) + (a2 + a3)) + ((a4 + a5) + (a6 + a7));
#pragma unroll
  for (int o = 8; o >= 1; o >>= 1) sum += __shfl_xor(sum, o, 16);
  float mu = sum * (1.0f / 128.0f);
  float e0 = a0 - mu, e1 = a1 - mu, e2 = a2 - mu, e3 = a3 - mu;
  float e4 = a4 - mu, e5 = a5 - mu, e6 = a6 - mu, e7 = a7 - mu;
  float vs = ((e0 * e0 + e1 * e1) + (e2 * e2 + e3 * e3)) +
             ((e4 * e4 + e5 * e5) + (e6 * e6 + e7 * e7));
#pragma unroll
  for (int o = 8; o >= 1; o >>= 1) vs += __shfl_xor(vs, o, 16);
  float inv = rsqrtf(vs * (1.0f / 128.0f) + EPS);

  float4 gg0 = *(const float4*)(g + d0);
  float4 gg1 = *(const float4*)(g + d0 + 4);
  float4 bl0 = *(const float4*)(bln + d0);
  float4 bl1 = *(const float4*)(bln + d0 + 4);
  out[0] = fmaxf(e0 * inv * gg0.x + bl0.x, 0.0f);
  out[1] = fmaxf(e1 * inv * gg0.y + bl0.y, 0.0f);
  out[2] = fmaxf(e2 * inv * gg0.z + bl0.z, 0.0f);
  out[3] = fmaxf(e3 * inv * gg0.w + bl0.w, 0.0f);
  out[4] = fmaxf(e4 * inv * gg1.x + bl1.x, 0.0f);
  out[5] = fmaxf(e5 * inv * gg1.y + bl1.y, 0.0f);
  out[6] = fmaxf(e6 * inv * gg1.z + bl1.z, 0.0f);
  out[7] = fmaxf(e7 * inv * gg1.w + bl1.w, 0.0f);
}

// P6a: pure gather1 + LN + ReLU -> y1 (fp16) in global. No LDS, no barrier,
// 64-VGPR target for 8 waves/SIMD residency (latency-bound random gather).
__global__ __launch_bounds__(256, 8) void k_gather1(
    const uint2* __restrict__ hb, const int4* __restrict__ meta,
    const u32* __restrict__ csr,
    const float* __restrict__ b, const float* __restrict__ g,
    const float* __restrict__ bln,
    u16* __restrict__ y1, int n) {
  const int tid = threadIdx.x;
  const int sl = tid & 15;
  const int row = blockIdx.x * 16 + (tid >> 4);
  float o[8];
  gather_ln_core(hb, meta, csr, b, g, bln, row, n, sl, o);
  if (row >= n) return;
  uint4 pk;
  pk.x = ((u32)f2h(o[1]) << 16) | (u32)f2h(o[0]);
  pk.y = ((u32)f2h(o[3]) << 16) | (u32)f2h(o[2]);
  pk.z = ((u32)f2h(o[5]) << 16) | (u32)f2h(o[4]);
  pk.w = ((u32)f2h(o[7]) << 16) | (u32)f2h(o[6]);
  *(uint4*)(y1 + (size_t)row * D + sl * 8) = pk;
}

// P6b: standalone GEMM2: y1 (fp16) @ W2 -> B (h2, fp8).
__global__ __launch_bounds__(256) void k_gemm2(const u16* __restrict__ y1,
                                               const u16* __restrict__ Wt2,
                                               u8* __restrict__ outB, int n) {
  gemm_body<false>(y1, Wt2, outB, n, blockIdx.x);
}

// P7: gather2 + LN + ReLU + residual -> fp32 out.
__global__ __launch_bounds__(256, 8) void k_gather2(
    const uint2* __restrict__ hb, const int4* __restrict__ meta,
    const u32* __restrict__ csr,
    const float* __restrict__ b, const float* __restrict__ g,
    const float* __restrict__ bln, const float* __restrict__ resid,
    float* __restrict__ outf, int n) {
  const int tid = threadIdx.x;
  const int sl = tid & 15;
  const int row = blockIdx.x * 16 + (tid >> 4);
  float o[8];
  gather_ln_core(hb, meta, csr, b, g, bln, row, n, sl, o);
  if (row >= n) return;
  size_t base = (size_t)row * D + sl * 8;
  float4 r0 = *(const float4*)(resid + base);
  float4 r1 = *(const float4*)(resid + base + 4);
  *(float4*)(outf + base) =
      make_float4(o[0] + r0.x, o[1] + r0.y, o[2] + r0.z, o[3] + r0.w);
  *(float4*)(outf + base + 4) =
      make_float4(o[4] + r1.x, o[5] + r1.y, o[6] + r1.z, o[7] + r1.w);
}

// ---------------------------------------------------------------------------
extern "C" void kernel_launch(void* const* d_in, const int* in_sizes, int n_in,
                              void* d_out, int out_size, void* d_ws, size_t ws_size,
                              hipStream_t stream) {
  const float* x    = (const float*)d_in[0];
  const int*   ei   = (const int*)d_in[1];
  const float* W1   = (const float*)d_in[2];
  const float* b1   = (const float*)d_in[3];
  const float* g1   = (const float*)d_in[4];
  const float* bl1  = (const float*)d_in[5];
  const float* W2   = (const float*)d_in[6];
  const float* b2   = (const float*)d_in[7];
  const float* g2   = (const float*)d_in[8];
  const float* bl2  = (const float*)d_in[9];

  const int N = in_sizes[0] / D;
  const int E = in_sizes[1] / 2;
  const int* src = ei;
  const int* dst = ei + E;

  const int EPB = (E + CB - 1) / CB;        // edges per count block
  const int GB  = (N + 63) / 64;            // gemm blocks
  const int RB  = (N + 15) / 16;            // gather blocks (16 rows each)
  const int ZB  = (N + 255) / 256;          // deg-zero blocks

  size_t off = 0;
  auto walloc = [&](size_t bytes) {
    void* p = (char*)d_ws + off;
    off = (off + bytes + 255) & ~(size_t)255;
    return p;
  };
  int*   deg   = (int*)walloc((size_t)N * 4);
  int*   cursor= (int*)walloc((size_t)N * 4);
  u32*   csr   = (u32*)walloc((size_t)E * 4 + 256);
  int4*  meta  = (int4*)walloc((size_t)N * 16);
  float* dinv  = (float*)walloc((size_t)N * 4);
  u8*    A     = (u8*)walloc((size_t)N * D);        // h1 (fp8 e4m3)
  u8*    B     = (u8*)walloc((size_t)N * D);        // h2 (fp8 e4m3)
  u16*   Wt1   = (u16*)walloc((size_t)D * D * 2);
  u16*   Wt2   = (u16*)walloc((size_t)D * D * 2);
  u16*   y1    = (u16*)walloc((size_t)N * D * 2);   // LN1 out (fp16)
  float* O     = (float*)d_out;

  // P0: weight converts || zero deg
  k_prep<<<128 + ZB, 256, 0, stream>>>(W1, W2, Wt1, Wt2, deg, N);
  // ph1: deg count (global atomics) || GEMM1 (x @ W1 -> A fp8)
  k_count_gemm1<<<CB + GB, 256, 0, stream>>>(dst, deg, E, EPB, x, Wt1, A, N);
  // ph2: scan -> meta/dinv/cursor
  k_scan<<<1, 1024, 0, stream>>>(deg, meta, dinv, cursor, N);
  // ph3: direct scatter with inline weight
  k_scatter2<<<512, 256, 0, stream>>>(src, dst, dinv, cursor, csr, E);
  // P6a: gather1 + LN + ReLU -> y1 (fp16)
  k_gather1<<<RB, 256, 0, stream>>>((const uint2*)A, meta, csr, b1, g1, bl1,
                                    y1, N);
  // P6b: GEMM2 -> B (fp8)
  k_gemm2<<<GB, 256, 0, stream>>>(y1, Wt2, B, N);
  // P7: gather2 + LN + ReLU + residual -> O
  k_gather2<<<RB, 256, 0, stream>>>((const uint2*)B, meta, csr,
                                    b2, g2, bl2, x, O, N);
}

// Round 4
// 193.801 us; speedup vs baseline: 1.4038x; 1.4038x over previous
//
#include <hip/hip_runtime.h>
#include <hip/hip_fp16.h>

#define D 128
#define EPS 1e-5f
#define KB 64          // coarse count/scatter blocks
#define NBSH 7         // bucket = dst >> 7
#define BUCKW 128      // dsts per bucket

typedef unsigned int u32;
typedef unsigned short u16;
typedef unsigned char u8;
typedef __attribute__((ext_vector_type(8))) _Float16 half8;  // mfma A/B frag
typedef __attribute__((ext_vector_type(4))) float f32x4;
typedef __attribute__((ext_vector_type(2))) float f32x2;

__device__ inline u16 f2h(float x) {
  _Float16 t = (_Float16)x;
  return __builtin_bit_cast(u16, t);
}
__device__ inline u8 f2fp8(float x) {
  return (u8)(__builtin_amdgcn_cvt_pk_fp8_f32(x, x, 0, false) & 0xff);
}

// ---------------------------------------------------------------------------
// P0: convert W1,W2 fp32[k][c] -> fp16 Wt[c][k].
__global__ __launch_bounds__(256) void k_prep(const float* __restrict__ W1,
                                              const float* __restrict__ W2,
                                              u16* __restrict__ Wt1,
                                              u16* __restrict__ Wt2) {
  int i = blockIdx.x * 256 + threadIdx.x;
  if (i < 2 * D * D) {
    const float* W = (i < D * D) ? W1 : W2;
    u16* Wt = (i < D * D) ? Wt1 : Wt2;
    int ii = i & (D * D - 1);
    int k = ii >> 7, c = ii & 127;
    Wt[c * D + k] = f2h(W[ii]);
  }
}

// ---------------------------------------------------------------------------
// LDS-free MFMA GEMM body; OUTPUT IS FP8 (e4m3). A-frag from global
// (contiguous 16B in k); B from Wt[c][k] (L2-hot); D: col=ct*16+m, row=q*4+reg.
template <bool F32IN>
__device__ __forceinline__ void gemm_body(const void* __restrict__ in_,
                                          const u16* __restrict__ Wt,
                                          u8* __restrict__ out, int nrows,
                                          int blk) {
  const int tid = threadIdx.x;
  const int lane = tid & 63, wv = tid >> 6;
  const int m = lane & 15, q = lane >> 4;
  const int r0 = blk * 64 + wv * 16;
  const int rowa = min(r0 + m, nrows - 1);

  f32x4 acc[8];
#pragma unroll
  for (int ct = 0; ct < 8; ct++) acc[ct] = (f32x4)(0.0f);

#pragma unroll
  for (int kk = 0; kk < 4; kk++) {
    const int kbase = kk * 32 + q * 8;
    half8 a;
    if (F32IN) {
      const float* in = (const float*)in_;
      float4 v0 = *(const float4*)(in + (size_t)rowa * D + kbase);
      float4 v1 = *(const float4*)(in + (size_t)rowa * D + kbase + 4);
      a[0] = (_Float16)v0.x; a[1] = (_Float16)v0.y;
      a[2] = (_Float16)v0.z; a[3] = (_Float16)v0.w;
      a[4] = (_Float16)v1.x; a[5] = (_Float16)v1.y;
      a[6] = (_Float16)v1.z; a[7] = (_Float16)v1.w;
    } else {
      const u16* in = (const u16*)in_;
      a = *(const half8*)(in + (size_t)rowa * D + kbase);
    }
#pragma unroll
    for (int ct = 0; ct < 8; ct++) {
      half8 b = *(const half8*)(Wt + (ct * 16 + m) * D + kbase);
      acc[ct] = __builtin_amdgcn_mfma_f32_16x16x32_f16(a, b, acc[ct], 0, 0, 0);
    }
  }

#pragma unroll
  for (int ct = 0; ct < 8; ct++) {
#pragma unroll
    for (int rg = 0; rg < 4; rg++) {
      int rr = r0 + q * 4 + rg;
      if (rr < nrows) out[(size_t)rr * D + ct * 16 + m] = f2fp8(acc[ct][rg]);
    }
  }
}

// ph1: coarse-bucket count, 8-deep batched (blocks [0,KB)) || GEMM1.
__global__ __launch_bounds__(256) void k_count_gemm1(
    const int* __restrict__ dst, int* __restrict__ cnt, int E, int NB, int EPB,
    const float* __restrict__ x, const u16* __restrict__ Wt1,
    u8* __restrict__ A, int nrows) {
  if (blockIdx.x < (u32)KB) {
    __shared__ int hist[512];
    const int k = blockIdx.x, tid = threadIdx.x;
    for (int i = tid; i < NB; i += 256) hist[i] = 0;
    __syncthreads();
    const int e0 = k * EPB, e1 = min(E, e0 + EPB);
    for (int base = e0 + tid; base < e1; base += 2048) {
      int dd[8];
#pragma unroll
      for (int i = 0; i < 8; i++) {
        int e = base + i * 256;
        dd[i] = (e < e1) ? dst[e] : -1;
      }
#pragma unroll
      for (int i = 0; i < 8; i++)
        if (dd[i] >= 0) atomicAdd(&hist[dd[i] >> NBSH], 1);
    }
    __syncthreads();
    for (int b = tid; b < NB; b += 256) cnt[b * KB + k] = hist[b];
  } else {
    gemm_body<true>(x, Wt1, A, nrows, blockIdx.x - KB);
  }
}

// ph2: parallel 3-phase exclusive scan of cnt[M] (bucket-major).
// 2a: per-block (1024 elem) reduce -> bsum.
__global__ __launch_bounds__(256) void k_scan_reduce(
    const int* __restrict__ cnt, int M, int* __restrict__ bsum) {
  const int b = blockIdx.x, t = threadIdx.x;
  const int lane = t & 63, w = t >> 6;
  int idx = b * 1024 + t * 4;
  int4 v = make_int4(0, 0, 0, 0);
  if (idx + 3 < M) {
    v = *(const int4*)(cnt + idx);
  } else {
    if (idx + 0 < M) v.x = cnt[idx + 0];
    if (idx + 1 < M) v.y = cnt[idx + 1];
    if (idx + 2 < M) v.z = cnt[idx + 2];
  }
  int s = v.x + v.y + v.z + v.w;
#pragma unroll
  for (int o = 1; o < 64; o <<= 1) s += __shfl_xor(s, o, 64);
  __shared__ int ws[4];
  if (lane == 0) ws[w] = s;
  __syncthreads();
  if (t == 0) bsum[b] = ws[0] + ws[1] + ws[2] + ws[3];
}

// 2b: tiny scan of block sums -> boff; also bsv[NB] = E.
__global__ __launch_bounds__(64) void k_scan_mid(const int* __restrict__ bsum,
                                                 int* __restrict__ boff,
                                                 int SB, int* __restrict__ bsv,
                                                 int NB, int E) {
  const int lane = threadIdx.x;
  int running = 0;
  for (int base = 0; base < SB; base += 64) {
    int i = base + lane;
    int v = (i < SB) ? bsum[i] : 0;
    int incl = v;
#pragma unroll
    for (int o = 1; o < 64; o <<= 1) {
      int t = __shfl_up(incl, o, 64);
      if (lane >= o) incl += t;
    }
    if (i < SB) boff[i] = running + incl - v;
    running += __shfl(incl, 63, 64);
  }
  if (lane == 0) bsv[NB] = E;
}

// 2c: per-block local scan + boff -> cnt[i]=excl, bsv at KB boundaries.
__global__ __launch_bounds__(256) void k_scan_apply(
    int* __restrict__ cnt, int M, const int* __restrict__ boff,
    int* __restrict__ bsv) {
  const int b = blockIdx.x, t = threadIdx.x;
  const int lane = t & 63, w = t >> 6;
  int idx = b * 1024 + t * 4;
  int4 v = make_int4(0, 0, 0, 0);
  if (idx + 3 < M) {
    v = *(const int4*)(cnt + idx);
  } else {
    if (idx + 0 < M) v.x = cnt[idx + 0];
    if (idx + 1 < M) v.y = cnt[idx + 1];
    if (idx + 2 < M) v.z = cnt[idx + 2];
  }
  int s = v.x + v.y + v.z + v.w;
  int incl = s;
#pragma unroll
  for (int o = 1; o < 64; o <<= 1) {
    int u = __shfl_up(incl, o, 64);
    if (lane >= o) incl += u;
  }
  __shared__ int ws[4];
  if (lane == 63) ws[w] = incl;
  __syncthreads();
  int wbase = 0;
#pragma unroll
  for (int j = 0; j < 4; j++)
    if (j < w) wbase += ws[j];
  int base = boff[b] + wbase + incl - s;  // exclusive prefix for idx
  int e0 = base, e1 = e0 + v.x, e2 = e1 + v.y, e3 = e2 + v.z;
  // idx is a multiple of 4; only idx itself can be a multiple of KB=64.
  if (idx < M) {
    cnt[idx] = e0;
    if ((idx & (KB - 1)) == 0) bsv[idx >> 6] = e0;
  }
  if (idx + 1 < M) cnt[idx + 1] = e1;
  if (idx + 2 < M) cnt[idx + 2] = e2;
  if (idx + 3 < M) cnt[idx + 3] = e3;
}

// ph3: scatter edges into bucket-grouped tmp via LDS cursors, 8-deep batched.
__global__ __launch_bounds__(256) void k_scatter(
    const int* __restrict__ src, const int* __restrict__ dst,
    const int* __restrict__ cnt, u32* __restrict__ tmp, int E, int NB,
    int EPB) {
  __shared__ int off[512];
  const int k = blockIdx.x, tid = threadIdx.x;
  for (int b = tid; b < NB; b += 256) off[b] = cnt[b * KB + k];
  __syncthreads();
  const int e0 = k * EPB, e1 = min(E, e0 + EPB);
  for (int base = e0 + tid; base < e1; base += 2048) {
    int dd[8], ss[8];
#pragma unroll
    for (int i = 0; i < 8; i++) {
      int e = base + i * 256;
      dd[i] = (e < e1) ? dst[e] : -1;
      ss[i] = (e < e1) ? src[e] : 0;
    }
#pragma unroll
    for (int i = 0; i < 8; i++) {
      if (dd[i] >= 0) {
        int p = atomicAdd(&off[dd[i] >> NBSH], 1);
        tmp[p] = (u32)ss[i] | ((u32)(dd[i] & (BUCKW - 1)) << 16);
      }
    }
  }
}

// ph4: one block per bucket: fine 128-bin LDS hist + scan -> deg/dinv/meta,
// then dst-sorted csr (entry = src).
__global__ __launch_bounds__(256) void k_bucket(
    const u32* __restrict__ tmp, const int* __restrict__ bsv,
    int4* __restrict__ meta, float* __restrict__ dinv,
    u32* __restrict__ csr, int N) {
  __shared__ int hist[BUCKW];
  __shared__ int sc[BUCKW];
  __shared__ int cur[BUCKW];
  const int b = blockIdx.x, tid = threadIdx.x;
  const int s0 = bsv[b], s1 = bsv[b + 1];
  if (tid < BUCKW) hist[tid] = 0;
  __syncthreads();
  for (int base = s0 + tid; base < s1; base += 1024) {
    int tt[4];
#pragma unroll
    for (int i = 0; i < 4; i++) {
      int idx = base + i * 256;
      tt[i] = (idx < s1) ? (int)tmp[idx] : -1;
    }
#pragma unroll
    for (int i = 0; i < 4; i++)
      if (tt[i] >= 0) atomicAdd(&hist[(tt[i] >> 16) & (BUCKW - 1)], 1);
  }
  __syncthreads();
  if (tid < BUCKW) sc[tid] = hist[tid];
  __syncthreads();
#pragma unroll
  for (int o = 1; o < BUCKW; o <<= 1) {
    int t = 0;
    if (tid < BUCKW && tid >= o) t = sc[tid - o];
    __syncthreads();
    if (tid < BUCKW) sc[tid] += t;
    __syncthreads();
  }
  if (tid < BUCKW) {
    int dg = hist[tid];
    int excl = sc[tid] - dg;
    cur[tid] = excl;
    int d = (b << NBSH) + tid;
    if (d < N) {
      float dv = rsqrtf((float)dg + 1.0f);
      meta[d] = make_int4(s0 + excl, dg, __builtin_bit_cast(int, dv), 0);
      dinv[d] = dv;
    }
  }
  __syncthreads();
  for (int base = s0 + tid; base < s1; base += 1024) {
    int tt[4];
#pragma unroll
    for (int i = 0; i < 4; i++) {
      int idx = base + i * 256;
      tt[i] = (idx < s1) ? (int)tmp[idx] : -1;
    }
#pragma unroll
    for (int i = 0; i < 4; i++) {
      if (tt[i] >= 0) {
        int r = atomicAdd(&cur[(tt[i] >> 16) & (BUCKW - 1)], 1);
        csr[s0 + r] = (u32)tt[i] & 0xffffu;
      }
    }
  }
}

// ph5: pack weights: csr entry src -> src | fp16(dinv[s]*dinv[d])<<16.
__global__ __launch_bounds__(256) void k_weights(
    const int4* __restrict__ meta, const float* __restrict__ dinv,
    u32* __restrict__ csr, int N) {
  int gid = blockIdx.x * 256 + threadIdx.x;
  int r = gid >> 2, j0 = gid & 3;
  if (r >= N) return;
  int4 mt = meta[r];
  float dv = __builtin_bit_cast(float, mt.z);
  for (int j = j0; j < mt.y; j += 4) {
    u32 s = csr[mt.x + j];
    float w = dinv[s] * dv;
    csr[mt.x + j] = s | ((u32)f2h(w) << 16);
  }
}

// ---------------------------------------------------------------------------
// Gather+LN core — FP8 h rows (128 B), fp32 accumulation.
// Row owned by 16 lanes, uint2 (8 fp8) per lane.
// csr entries fetched as UNIFORM per-group vector loads (HW broadcast) —
// affine addresses, no ds_bpermute in the chase chain. 8 row loads issued
// back-to-back per window.
#define ACC_EDGE(vv, ee)                                                     \
  {                                                                          \
    float ww = (float)__builtin_bit_cast(_Float16, (u16)((ee) >> 16));       \
    f32x2 p_;                                                                \
    p_ = __builtin_amdgcn_cvt_pk_f32_fp8(vv.x, false);                       \
    acc[0] = fmaf(p_[0], ww, acc[0]); acc[1] = fmaf(p_[1], ww, acc[1]);      \
    p_ = __builtin_amdgcn_cvt_pk_f32_fp8(vv.x, true);                        \
    acc[2] = fmaf(p_[0], ww, acc[2]); acc[3] = fmaf(p_[1], ww, acc[3]);      \
    p_ = __builtin_amdgcn_cvt_pk_f32_fp8(vv.y, false);                       \
    acc[4] = fmaf(p_[0], ww, acc[4]); acc[5] = fmaf(p_[1], ww, acc[5]);      \
    p_ = __builtin_amdgcn_cvt_pk_f32_fp8(vv.y, true);                        \
    acc[6] = fmaf(p_[0], ww, acc[6]); acc[7] = fmaf(p_[1], ww, acc[7]);      \
  }

__device__ __forceinline__ void gather_ln_core(
    const uint2* __restrict__ hb, const int4* __restrict__ meta,
    const u32* __restrict__ csr, const float* __restrict__ b,
    const float* __restrict__ g, const float* __restrict__ bln,
    int row, int n, int sl, float out[8]) {
  const bool valid = row < n;
  const int rc = valid ? row : 0;
  int4 mt = meta[rc];
  int beg = mt.x;
  int cnt = valid ? mt.y : 0;
  float dv = __builtin_bit_cast(float, mt.z);
  float sn = dv * dv;

  float acc[8];
  {
    uint2 su = hb[(size_t)rc * 16 + sl];
    f32x2 p0 = __builtin_amdgcn_cvt_pk_f32_fp8(su.x, false);
    f32x2 p1 = __builtin_amdgcn_cvt_pk_f32_fp8(su.x, true);
    f32x2 p2 = __builtin_amdgcn_cvt_pk_f32_fp8(su.y, false);
    f32x2 p3 = __builtin_amdgcn_cvt_pk_f32_fp8(su.y, true);
    acc[0] = p0[0] * sn; acc[1] = p0[1] * sn;
    acc[2] = p1[0] * sn; acc[3] = p1[1] * sn;
    acc[4] = p2[0] * sn; acc[5] = p2[1] * sn;
    acc[6] = p3[0] * sn; acc[7] = p3[1] * sn;
  }

  int cm = max(cnt, __shfl_xor(cnt, 16, 64));
  cm = max(cm, __shfl_xor(cm, 32, 64));

  for (int j0 = 0; j0 < cm; j0 += 8) {
    u32 e[8];
#pragma unroll
    for (int jj = 0; jj < 8; jj++) {
      int j = j0 + jj;
      e[jj] = (j < cnt) ? csr[beg + j] : 0u;   // uniform per 16-lane group
    }
    uint2 v[8];
#pragma unroll
    for (int jj = 0; jj < 8; jj++)
      v[jj] = hb[(size_t)(e[jj] & 0xffffu) * 16 + sl];
#pragma unroll
    for (int jj = 0; jj < 8; jj++) ACC_EDGE(v[jj], e[jj]);
  }

  // ---- LayerNorm over 128 cols, 8 per lane across 16 lanes ----
  int d0 = sl * 8;
  float4 bb0 = *(const float4*)(b + d0);
  float4 bb1 = *(const float4*)(b + d0 + 4);
  float a0 = acc[0] + bb0.x, a1 = acc[1] + bb0.y;
  float a2 = acc[2] + bb0.z, a3 = acc[3] + bb0.w;
  float a4 = acc[4] + bb1.x, a5 = acc[5] + bb1.y;
  float a6 = acc[6] + bb1.z, a7 = acc[7] + bb1.w;

  float sum = ((a0 + a1) + (a2 + a3)) + ((a4 + a5) + (a6 + a7));
#pragma unroll
  for (int o = 8; o >= 1; o >>= 1) sum += __shfl_xor(sum, o, 16);
  float mu = sum * (1.0f / 128.0f);
  float e0 = a0 - mu, e1 = a1 - mu, e2 = a2 - mu, e3 = a3 - mu;
  float e4 = a4 - mu, e5 = a5 - mu, e6 = a6 - mu, e7 = a7 - mu;
  float vs = ((e0 * e0 + e1 * e1) + (e2 * e2 + e3 * e3)) +
             ((e4 * e4 + e5 * e5) + (e6 * e6 + e7 * e7));
#pragma unroll
  for (int o = 8; o >= 1; o >>= 1) vs += __shfl_xor(vs, o, 16);
  float inv = rsqrtf(vs * (1.0f / 128.0f) + EPS);

  float4 gg0 = *(const float4*)(g + d0);
  float4 gg1 = *(const float4*)(g + d0 + 4);
  float4 bl0 = *(const float4*)(bln + d0);
  float4 bl1 = *(const float4*)(bln + d0 + 4);
  out[0] = fmaxf(e0 * inv * gg0.x + bl0.x, 0.0f);
  out[1] = fmaxf(e1 * inv * gg0.y + bl0.y, 0.0f);
  out[2] = fmaxf(e2 * inv * gg0.z + bl0.z, 0.0f);
  out[3] = fmaxf(e3 * inv * gg0.w + bl0.w, 0.0f);
  out[4] = fmaxf(e4 * inv * gg1.x + bl1.x, 0.0f);
  out[5] = fmaxf(e5 * inv * gg1.y + bl1.y, 0.0f);
  out[6] = fmaxf(e6 * inv * gg1.z + bl1.z, 0.0f);
  out[7] = fmaxf(e7 * inv * gg1.w + bl1.w, 0.0f);
}

// P6a: pure gather1 + LN + ReLU -> y1 (fp16) in global. No LDS, no barrier,
// 64-VGPR target for 8 waves/SIMD residency (latency-bound random gather).
__global__ __launch_bounds__(256, 8) void k_gather1(
    const uint2* __restrict__ hb, const int4* __restrict__ meta,
    const u32* __restrict__ csr,
    const float* __restrict__ b, const float* __restrict__ g,
    const float* __restrict__ bln,
    u16* __restrict__ y1, int n) {
  const int tid = threadIdx.x;
  const int sl = tid & 15;
  const int row = blockIdx.x * 16 + (tid >> 4);
  float o[8];
  gather_ln_core(hb, meta, csr, b, g, bln, row, n, sl, o);
  if (row >= n) return;
  uint4 pk;
  pk.x = ((u32)f2h(o[1]) << 16) | (u32)f2h(o[0]);
  pk.y = ((u32)f2h(o[3]) << 16) | (u32)f2h(o[2]);
  pk.z = ((u32)f2h(o[5]) << 16) | (u32)f2h(o[4]);
  pk.w = ((u32)f2h(o[7]) << 16) | (u32)f2h(o[6]);
  *(uint4*)(y1 + (size_t)row * D + sl * 8) = pk;
}

// P6b: standalone GEMM2: y1 (fp16) @ W2 -> B (h2, fp8).
__global__ __launch_bounds__(256) void k_gemm2(const u16* __restrict__ y1,
                                               const u16* __restrict__ Wt2,
                                               u8* __restrict__ outB, int n) {
  gemm_body<false>(y1, Wt2, outB, n, blockIdx.x);
}

// P7: gather2 + LN + ReLU + residual -> fp32 out.
__global__ __launch_bounds__(256, 8) void k_gather2(
    const uint2* __restrict__ hb, const int4* __restrict__ meta,
    const u32* __restrict__ csr,
    const float* __restrict__ b, const float* __restrict__ g,
    const float* __restrict__ bln, const float* __restrict__ resid,
    float* __restrict__ outf, int n) {
  const int tid = threadIdx.x;
  const int sl = tid & 15;
  const int row = blockIdx.x * 16 + (tid >> 4);
  float o[8];
  gather_ln_core(hb, meta, csr, b, g, bln, row, n, sl, o);
  if (row >= n) return;
  size_t base = (size_t)row * D + sl * 8;
  float4 r0 = *(const float4*)(resid + base);
  float4 r1 = *(const float4*)(resid + base + 4);
  *(float4*)(outf + base) =
      make_float4(o[0] + r0.x, o[1] + r0.y, o[2] + r0.z, o[3] + r0.w);
  *(float4*)(outf + base + 4) =
      make_float4(o[4] + r1.x, o[5] + r1.y, o[6] + r1.z, o[7] + r1.w);
}

// ---------------------------------------------------------------------------
extern "C" void kernel_launch(void* const* d_in, const int* in_sizes, int n_in,
                              void* d_out, int out_size, void* d_ws, size_t ws_size,
                              hipStream_t stream) {
  const float* x    = (const float*)d_in[0];
  const int*   ei   = (const int*)d_in[1];
  const float* W1   = (const float*)d_in[2];
  const float* b1   = (const float*)d_in[3];
  const float* g1   = (const float*)d_in[4];
  const float* bl1  = (const float*)d_in[5];
  const float* W2   = (const float*)d_in[6];
  const float* b2   = (const float*)d_in[7];
  const float* g2   = (const float*)d_in[8];
  const float* bl2  = (const float*)d_in[9];

  const int N = in_sizes[0] / D;
  const int E = in_sizes[1] / 2;
  const int* src = ei;
  const int* dst = ei + E;

  const int NB  = (N + BUCKW - 1) / BUCKW;  // coarse buckets
  const int M   = NB * KB;
  const int EPB = (E + KB - 1) / KB;        // edges per count/scatter block
  const int GB  = (N + 63) / 64;            // gemm blocks
  const int RB  = (N + 15) / 16;            // gather blocks (16 rows each)
  const int SB  = (M + 1023) / 1024;        // scan blocks

  size_t off = 0;
  auto walloc = [&](size_t bytes) {
    void* p = (char*)d_ws + off;
    off = (off + bytes + 255) & ~(size_t)255;
    return p;
  };
  int*   cnt   = (int*)walloc((size_t)M * 4);
  int*   bsum  = (int*)walloc((size_t)SB * 4);
  int*   boff  = (int*)walloc((size_t)SB * 4);
  int*   bsv   = (int*)walloc((size_t)(NB + 1) * 4);
  u32*   tmp   = (u32*)walloc((size_t)E * 4);
  u32*   csr   = (u32*)walloc((size_t)E * 4);
  int4*  meta  = (int4*)walloc((size_t)N * 16);
  float* dinv  = (float*)walloc((size_t)N * 4);
  u8*    A     = (u8*)walloc((size_t)N * D);        // h1 (fp8 e4m3)
  u8*    B     = (u8*)walloc((size_t)N * D);        // h2 (fp8 e4m3)
  u16*   Wt1   = (u16*)walloc((size_t)D * D * 2);
  u16*   Wt2   = (u16*)walloc((size_t)D * D * 2);
  u16*   y1    = (u16*)walloc((size_t)N * D * 2);   // LN1 out (fp16)
  float* O     = (float*)d_out;

  // P0: weight converts
  k_prep<<<(2 * D * D + 255) / 256, 256, 0, stream>>>(W1, W2, Wt1, Wt2);
  // ph1: coarse count || GEMM1 (x @ W1 -> A fp8)
  k_count_gemm1<<<KB + GB, 256, 0, stream>>>(dst, cnt, E, NB, EPB, x, Wt1, A, N);
  // ph2: parallel scan (reduce -> mid -> apply)
  k_scan_reduce<<<SB, 256, 0, stream>>>(cnt, M, bsum);
  k_scan_mid<<<1, 64, 0, stream>>>(bsum, boff, SB, bsv, NB, E);
  k_scan_apply<<<SB, 256, 0, stream>>>(cnt, M, boff, bsv);
  // ph3: scatter into buckets
  k_scatter<<<KB, 256, 0, stream>>>(src, dst, cnt, tmp, E, NB, EPB);
  // ph4: per-bucket fine sort -> csr + meta + dinv
  k_bucket<<<NB, 256, 0, stream>>>(tmp, bsv, meta, dinv, csr, N);
  // ph5: pack weights
  k_weights<<<(N * 4 + 255) / 256, 256, 0, stream>>>(meta, dinv, csr, N);
  // P6a: gather1 + LN + ReLU -> y1 (fp16)
  k_gather1<<<RB, 256, 0, stream>>>((const uint2*)A, meta, csr, b1, g1, bl1,
                                    y1, N);
  // P6b: GEMM2 -> B (fp8)
  k_gemm2<<<GB, 256, 0, stream>>>(y1, Wt2, B, N);
  // P7: gather2 + LN + ReLU + residual -> O
  k_gather2<<<RB, 256, 0, stream>>>((const uint2*)B, meta, csr,
                                    b2, g2, bl2, x, O, N);
}